// Round 8
// baseline (352.475 us; speedup 1.0000x reference)
//
#include <hip/hip_runtime.h>
#include <hip/hip_bf16.h>
#include <cstddef>

#define N_NODES 50000
#define N_EDGES 1600000
#define IN_DIM 128
#define OUT_DIM 16
#define N_HEADS 8
#define QKV_DIM 128               // N_HEADS * OUT_DIM
#define HS_STRIDE 136             // padded LDS row stride (u16) for h/out staging

#define SUBB 3125                 // N_NODES/16 sub-buckets (16 dst nodes each)
#define BCAP 1024                 // cap per bucket (lambda=512, >20 sigma)
#define BH_CHUNK 8192             // edges per scatter block
#define BH_BLOCKS 196             // 196*8192 = 1,605,632 >= 1.6M
#define GEMM_M 64                 // gemm tile rows
#define GEMM_BLOCKS 782           // ceil(50000/64)
#define FUSED_BLOCKS (BH_BLOCKS + GEMM_BLOCKS)
#define AGG_BLOCKS (SUBB * 8)     // bucket x head

typedef __hip_bfloat16 bf16;
typedef short bf16x8 __attribute__((ext_vector_type(8)));
typedef float f32x4  __attribute__((ext_vector_type(4)));

__device__ __forceinline__ float b2f(bf16 x) { return __bfloat162float(x); }

__device__ __forceinline__ float u16tof(unsigned int u) {
    unsigned int x = u << 16;
    float f;
    __builtin_memcpy(&f, &x, 4);
    return f;
}

__device__ __forceinline__ unsigned short f2bf(float v) {
    bf16 b = __float2bfloat16(v);
    unsigned short u;
    __builtin_memcpy(&u, &b, 2);
    return u;
}

__global__ __launch_bounds__(256) void sentinel_kernel(unsigned short* __restrict__ out, int n) {
    int i = blockIdx.x * 256 + threadIdx.x;
    if (i < n) out[i] = 0x42C8;
}

// ---------------------------------------------------------------------------
// prep: self-probe input dtype, publish flag, repack Wq|Wk|Wv into MFMA
// B-fragment order + fp32 bias vector.
// ---------------------------------------------------------------------------
__global__ __launch_bounds__(256) void prep_kernel(
    const unsigned short* __restrict__ hraw,
    const void* __restrict__ Wqr, const void* __restrict__ bqr,
    const void* __restrict__ Wkr, const void* __restrict__ bkr,
    const void* __restrict__ Wvr, const void* __restrict__ bvr,
    int* __restrict__ flag,
    unsigned short* __restrict__ Wfrag, float* __restrict__ bias_f)
{
    __shared__ int red[256];
    const int t   = threadIdx.x;
    const int tid = blockIdx.x * 256 + t;

    int cnt = 0;
    for (int i = t; i < 8192; i += 256) {
        unsigned short u = hraw[i];
        int e = (u >> 7) & 0xFF;
        if (e == 0xFF || e > 0x85 || (e == 0 && (u & 0x7F) != 0)) cnt++;
    }
    red[t] = cnt;
    __syncthreads();
    for (int s = 128; s > 0; s >>= 1) {
        if (t < s) red[t] += red[t + s];
        __syncthreads();
    }
    const bool f32 = (red[0] > 100);
    if (blockIdx.x == 0 && t == 0) *flag = red[0];

    if (tid < 384) {
        int mat = tid >> 7, c = tid & 127;
        const void* bp = (mat == 0) ? bqr : (mat == 1) ? bkr : bvr;
        bias_f[tid] = f32 ? ((const float*)bp)[c] : b2f(((const bf16*)bp)[c]);
    }

    int l  = tid & 63;
    int s  = (tid >> 6) & 3;
    int nt = tid >> 8;
    int n  = nt * 16 + (l & 15);
    int k0 = s * 32 + (l >> 4) * 8;
    int mat = n >> 7, c = n & 127;
    const void* Wp = (mat == 0) ? Wqr : (mat == 1) ? Wkr : Wvr;

    unsigned short v[8];
#pragma unroll
    for (int j = 0; j < 8; ++j) {
        int k = k0 + j;
        float w = f32 ? ((const float*)Wp)[k * QKV_DIM + c]
                      : b2f(((const bf16*)Wp)[k * QKV_DIM + c]);
        v[j] = f2bf(w);
    }
    ushort4* o = (ushort4*)(Wfrag + (size_t)tid * 8);
    o[0] = make_ushort4(v[0], v[1], v[2], v[3]);
    o[1] = make_ushort4(v[4], v[5], v[6], v[7]);
}

// ---------------------------------------------------------------------------
// FUSED kernel (R6-verified): blocks [0,196) = scatter (direct in-window
//   placement); blocks [196,978) = MFMA projection GEMM, M=64.
// NEW: flush writes HEAD-MAJOR layouts:
//   QH[head][node][16 bf16]                (32 B per node-head, 1.6 MB/head)
//   KVH[head][node][K 16 bf16 | V 16 bf16] (64 B per node-head, 3.2 MB/head)
// ---------------------------------------------------------------------------
__global__ __launch_bounds__(256) void fused_gs_kernel(
    const void* __restrict__ hraw,
    const unsigned short* __restrict__ Wfrag, const float* __restrict__ bias_f,
    const int* __restrict__ flag,
    unsigned short* __restrict__ Qt, unsigned short* __restrict__ KVt,
    const int* __restrict__ src, const int* __restrict__ dst,
    unsigned int* __restrict__ packed, unsigned int* __restrict__ offcnt)
{
    __shared__ __align__(16) unsigned char arena[GEMM_M * HS_STRIDE * 2];  // 17,408 B
    const int t = threadIdx.x;

    if (blockIdx.x < BH_BLOCKS) {
        // ----------------- scatter branch -----------------
        int* lcnt = (int*)arena;                        // 12,500 B
        int* sm   = (int*)(arena + 12544);              // 16 B scratch

        const int b    = blockIdx.x;
        const int base = b * BH_CHUNK;
        const int nb   = min(N_EDGES - base, BH_CHUNK);

        for (int i = t; i < SUBB; i += 256) lcnt[i] = 0;
        __syncthreads();

        for (int i = t; i < nb; i += 256)
            atomicAdd(&lcnt[dst[base + i] >> 4], 1);
        __syncthreads();

        {
            const int lane = t & 63;
            const int wave = t >> 6;
            const int i0   = t * 13;

            int xs[13];
            int ssum = 0;
#pragma unroll
            for (int j = 0; j < 13; ++j) {
                int i = i0 + j;
                int x = (i < SUBB) ? lcnt[i] : 0;
                xs[j] = x;
                ssum += x;
            }
            int v = ssum;
#pragma unroll
            for (int sh = 1; sh < 64; sh <<= 1) {
                int a = __shfl_up(v, sh);
                if (lane >= sh) v += a;
            }
            if (lane == 63) sm[wave] = v;
            __syncthreads();
            int run = v - ssum;
#pragma unroll
            for (int w = 0; w < 4; ++w)
                if (w < wave) run += sm[w];
#pragma unroll
            for (int j = 0; j < 13; ++j) {
                int i = i0 + j;
                if (i < SUBB) {
                    offcnt[(size_t)b * SUBB + i] =
                        ((unsigned int)run << 16) | (unsigned int)xs[j];
                    lcnt[i] = run;
                    run += xs[j];
                }
            }
            __syncthreads();
        }

        for (int i = t; i < nb; i += 256) {
            int d = dst[base + i];
            int bk = d >> 4;
            int pos = atomicAdd(&lcnt[bk], 1);
            packed[base + pos] = (unsigned int)src[base + i] | ((unsigned int)(d & 15) << 16);
        }

    } else {
        // ----------------- gemm branch -----------------
        unsigned short* smem = (unsigned short*)arena;   // 64 x 136 u16

        const bool f32 = (*flag > 100);
        const int m0 = (blockIdx.x - BH_BLOCKS) * GEMM_M;

#pragma unroll
        for (int it = 0; it < 8; ++it) {
            int idx = it * 1024 + t * 4;
            int r = idx >> 7, k = idx & 127;
            int row = m0 + r;
            ushort4 w4 = make_ushort4(0, 0, 0, 0);
            if (row < N_NODES) {
                if (f32) {
                    float4 v4 = ((const float4*)hraw)[(size_t)row * 32 + (k >> 2)];
                    w4 = make_ushort4(f2bf(v4.x), f2bf(v4.y), f2bf(v4.z), f2bf(v4.w));
                } else {
                    uint2 u = ((const uint2*)hraw)[(size_t)row * 32 + (k >> 2)];
                    w4 = make_ushort4((unsigned short)(u.x & 0xffffu), (unsigned short)(u.x >> 16),
                                      (unsigned short)(u.y & 0xffffu), (unsigned short)(u.y >> 16));
                }
            }
            *(ushort4*)&smem[r * HS_STRIDE + k] = w4;
        }
        __syncthreads();

        const int lane = t & 63;
        const int wave = t >> 6;
        const int qd   = lane >> 4;
        const int ln15 = lane & 15;

        bf16x8 afr[4][4];
#pragma unroll
        for (int ms = 0; ms < 4; ++ms)
#pragma unroll
            for (int s = 0; s < 4; ++s)
                afr[ms][s] = *(const bf16x8*)&smem[(ms * 16 + ln15) * HS_STRIDE + s * 32 + qd * 8];

        __syncthreads();   // smem reused for output staging

        // 3 phases: p=0 -> Q cols, p=1 -> K cols, p=2 -> V cols
#pragma unroll
        for (int p = 0; p < 3; ++p) {
#pragma unroll
            for (int ii = 0; ii < 2; ++ii) {
                const int i   = 2 * p + ii;
                const int nt  = wave + i * 4;
                const int col = nt * 16 + ln15;
                const float bs = bias_f[col];
                const int c127 = col & 127;

                bf16x8 bfr[4];
#pragma unroll
                for (int s = 0; s < 4; ++s)
                    bfr[s] = *(const bf16x8*)(Wfrag + ((size_t)(nt * 4 + s) * 64 + lane) * 8);

#pragma unroll
                for (int ms = 0; ms < 4; ++ms) {
                    f32x4 acc = {0.f, 0.f, 0.f, 0.f};
#pragma unroll
                    for (int s = 0; s < 4; ++s)
                        acc = __builtin_amdgcn_mfma_f32_16x16x32_bf16(afr[ms][s], bfr[s], acc, 0, 0, 0);
#pragma unroll
                    for (int r = 0; r < 4; ++r) {
                        int rl = ms * 16 + qd * 4 + r;
                        smem[rl * HS_STRIDE + c127] = f2bf(acc[r] + bs);
                    }
                }
            }
            __syncthreads();
            if (p == 0) {
                // Q flush: cols [8c,8c+8) = head c>>1, dims (c&1)*8..
                for (int q = t; q < 1024; q += 256) {
                    int row = q >> 4, c = q & 15;
                    int grow = m0 + row;
                    if (grow < N_NODES) {
                        int head = c >> 1, half = c & 1;
                        ((uint4*)Qt)[(size_t)head * (N_NODES * 2) + grow * 2 + half] =
                            *(const uint4*)&smem[row * HS_STRIDE + c * 8];
                    }
                }
            } else {
                // K/V flush: cols [4g,4g+4) = head g>>2, quart g&3
                for (int q = t; q < 2048; q += 256) {
                    int row = q >> 5, g = q & 31;
                    int grow = m0 + row;
                    if (grow < N_NODES) {
                        int head = g >> 2, quart = g & 3;
                        ((uint2*)KVt)[(size_t)head * (N_NODES * 8) + grow * 8
                                      + ((p == 1) ? 0 : 4) + quart] =
                            *(const uint2*)&smem[row * HS_STRIDE + g * 4];
                    }
                }
            }
            __syncthreads();
        }
    }
}

// ---------------------------------------------------------------------------
// sortbk: one block per bucket; run reconstruct + 16-way LDS sort (the
// R6-verified agg front), then writes the sorted edge list + per-dst counts
// to global so the 8 per-head agg blocks don't re-sort.
// ---------------------------------------------------------------------------
__global__ __launch_bounds__(256) void sortbk_kernel(
    const unsigned int* __restrict__ packed, const unsigned int* __restrict__ offcnt,
    unsigned short* __restrict__ gsorted, int* __restrict__ gcnt)
{
    __shared__ unsigned int   lds_pk[BCAP];
    __shared__ unsigned short lds_src[BCAP];
    __shared__ int runoff[BH_BLOCKS], runcnt[BH_BLOCKS], runpfx[BH_BLOCKS];
    __shared__ int cnt16[16], base16[16], cur16[16];
    __shared__ int wsum[4];
    __shared__ int nb_s;

    const int sb = blockIdx.x;
    const int t  = threadIdx.x;

    if (t < 16) { cnt16[t] = 0; cur16[t] = 0; }
    if (t < BH_BLOCKS) {
        unsigned int oc = offcnt[(size_t)t * SUBB + sb];
        runoff[t] = t * BH_CHUNK + (int)(oc >> 16);
        runcnt[t] = (int)(oc & 0xffffu);
    }
    __syncthreads();

    {
        const int lane = t & 63;
        const int wv   = t >> 6;
        int x = (t < BH_BLOCKS) ? runcnt[t] : 0;
        int v = x;
#pragma unroll
        for (int sh = 1; sh < 64; sh <<= 1) {
            int a = __shfl_up(v, sh);
            if (lane >= sh) v += a;
        }
        if (lane == 63) wsum[wv] = v;
        __syncthreads();
#pragma unroll
        for (int w = 0; w < 4; ++w)
            if (w < wv) v += wsum[w];
        if (t < BH_BLOCKS) runpfx[t] = v - x;
        if (t == 0) nb_s = wsum[0] + wsum[1] + wsum[2] + wsum[3];
        __syncthreads();
    }
    const int nb = min(nb_s, BCAP);

    for (int r = t; r < BH_BLOCKS; r += 256) {
        int ro = runoff[r], rc = runcnt[r], rp = runpfx[r];
        for (int j = 0; j < rc; ++j) {
            int dpos = rp + j;
            if (dpos < BCAP) {
                unsigned int pk = packed[ro + j];
                lds_pk[dpos] = pk;
                atomicAdd(&cnt16[(pk >> 16) & 15], 1);
            }
        }
    }
    __syncthreads();
    if (t == 0) {
        int acc = 0;
#pragma unroll
        for (int i = 0; i < 16; ++i) { base16[i] = acc; acc += cnt16[i]; }
    }
    __syncthreads();
    for (int j = t; j < nb; j += 256) {
        unsigned int pk = lds_pk[j];
        int dl = (pk >> 16) & 15;
        int pos = base16[dl] + atomicAdd(&cur16[dl], 1);
        lds_src[pos] = (unsigned short)(pk & 0xffffu);
    }
    __syncthreads();

    for (int j = t; j < nb; j += 256)
        gsorted[(size_t)sb * BCAP + j] = lds_src[j];
    if (t < 16) gcnt[sb * 16 + t] = cnt16[t];
}

// ---------------------------------------------------------------------------
// Aggregation, head-partitioned: block = (bucket, head), blockIdx%8 = head
// so all blocks of head h land on XCD h (round-robin dispatch) and gather
// from a resident 3.2 MB KVH slice. 4-lane group per edge: u=0,1 hold K
// halves (dot), u=2,3 hold V halves (accumulate). Streaming traffic
// (gsorted, Q, out) is nontemporal to protect KV residency.
// ---------------------------------------------------------------------------
__global__ __launch_bounds__(256) void bucket_agg_kernel(
    const unsigned short* __restrict__ QH, const unsigned short* __restrict__ KVH,
    const unsigned short* __restrict__ gsorted, const int* __restrict__ gcnt,
    const int* __restrict__ flag, void* __restrict__ out)
{
    __shared__ unsigned short lds_src[BCAP];
    __shared__ int cnt16[16], base16[16];
    __shared__ int tot_s;

    const int sb = blockIdx.x >> 3;
    const int hh = blockIdx.x & 7;
    const int t  = threadIdx.x;

    if (t < 16) cnt16[t] = gcnt[sb * 16 + t];
    __syncthreads();
    if (t == 0) {
        int acc = 0;
#pragma unroll
        for (int i = 0; i < 16; ++i) { base16[i] = acc; acc += cnt16[i]; }
        tot_s = acc;
    }
    __syncthreads();
    const int total = tot_s;
    for (int j = t; j < total; j += 256)
        lds_src[j] = __builtin_nontemporal_load(&gsorted[(size_t)sb * BCAP + j]);
    __syncthreads();

    const int wave = t >> 6;
    const int lane = t & 63;
    const int g4   = lane >> 2;
    const int u    = lane & 3;
    const bool of32 = (*flag > 100);

    const uint4* KV4 = (const uint4*)KVH;
    const unsigned int* QW = (const unsigned int*)QH;
    const size_t kvbase = (size_t)hh * (N_NODES * 4);   // uint4 units
    const size_t qwbase = (size_t)hh * (N_NODES * 8);   // uint units

    for (int dl = wave; dl < 16; dl += 4) {
        const int d = sb * 16 + dl;

        const unsigned int* qp = QW + qwbase + (size_t)d * 8 + (u & 1) * 4;
        unsigned int qw0 = __builtin_nontemporal_load(qp + 0);
        unsigned int qw1 = __builtin_nontemporal_load(qp + 1);
        unsigned int qw2 = __builtin_nontemporal_load(qp + 2);
        unsigned int qw3 = __builtin_nontemporal_load(qp + 3);
        float qf[8];
        qf[0] = u16tof(qw0 & 0xffffu); qf[1] = u16tof(qw0 >> 16);
        qf[2] = u16tof(qw1 & 0xffffu); qf[3] = u16tof(qw1 >> 16);
        qf[4] = u16tof(qw2 & 0xffffu); qf[5] = u16tof(qw2 >> 16);
        qf[6] = u16tof(qw3 & 0xffffu); qf[7] = u16tof(qw3 >> 16);

        const int off = base16[dl];
        const int nd  = cnt16[dl];

        float a[8] = {0.f, 0.f, 0.f, 0.f, 0.f, 0.f, 0.f, 0.f};
        float zz = 0.f;

        for (int j = 0; j < nd; j += 16) {
            const int ei = j + g4;
            const float msk = (ei < nd) ? 1.f : 0.f;
            const int e = (ei < nd) ? (int)lds_src[off + ei] : 0;
            uint4 kv = KV4[kvbase + (size_t)e * 4 + u];
            float kf[8];
            kf[0] = u16tof(kv.x & 0xffffu); kf[1] = u16tof(kv.x >> 16);
            kf[2] = u16tof(kv.y & 0xffffu); kf[3] = u16tof(kv.y >> 16);
            kf[4] = u16tof(kv.z & 0xffffu); kf[5] = u16tof(kv.z >> 16);
            kf[6] = u16tof(kv.w & 0xffffu); kf[7] = u16tof(kv.w >> 16);

            float pp = 0.f;
#pragma unroll
            for (int i = 0; i < 8; ++i) pp = fmaf(kf[i], qf[i], pp);
            pp = (u < 2) ? pp : 0.f;
            pp += __shfl_xor(pp, 1);
            pp += __shfl_xor(pp, 2);
            float sc = __expf(__builtin_amdgcn_fmed3f(pp * 0.25f, -5.f, 5.f)) * msk;
#pragma unroll
            for (int i = 0; i < 8; ++i) a[i] = fmaf(kf[i], sc, a[i]);
            zz += sc;
        }

#pragma unroll
        for (int s = 4; s <= 32; s <<= 1) {
#pragma unroll
            for (int i = 0; i < 8; ++i) a[i] += __shfl_xor(a[i], s);
            zz += __shfl_xor(zz, s);
        }

        const float inv = 1.f / (zz + 1e-6f);

        if (g4 == 0 && u >= 2) {
            const int dbase = (u - 2) * 8;
            if (of32) {
                float* op = (float*)out + (size_t)d * 128 + hh * 16 + dbase;
#pragma unroll
                for (int i = 0; i < 8; ++i)
                    __builtin_nontemporal_store(a[i] * inv, op + i);
            } else {
                unsigned int* op = (unsigned int*)out + (size_t)d * 64 + hh * 8 + (u - 2) * 4;
#pragma unroll
                for (int i = 0; i < 4; ++i) {
                    unsigned int w = ((unsigned int)f2bf(a[2 * i + 1] * inv) << 16)
                                   | f2bf(a[2 * i] * inv);
                    __builtin_nontemporal_store(w, op + i);
                }
            }
        }
    }
}

// ---------------------------------------------------------------------------
extern "C" void kernel_launch(void* const* d_in, const int* in_sizes, int n_in,
                              void* d_out, int out_size, void* d_ws, size_t ws_size,
                              hipStream_t stream)
{
    const void* h  = d_in[0];
    const void* Wq = d_in[1];
    const void* bq = d_in[2];
    const void* Wk = d_in[3];
    const void* bk = d_in[4];
    const void* Wv = d_in[5];
    const void* bv = d_in[6];
    const int*  src = (const int*)d_in[7];
    const int*  dst = (const int*)d_in[8];

    const size_t NQ = (size_t)N_NODES * QKV_DIM;   // 6,400,000
    const size_t WFRAG_N = 24 * 4 * 64 * 8;        // 49,152
    const size_t PACKED_N = (size_t)BH_BLOCKS * BH_CHUNK;   // 1,605,632
    const size_t OFFCNT_N = (size_t)BH_BLOCKS * SUBB;       // 612,500
    const size_t GS_N   = (size_t)SUBB * BCAP;              // 3,200,000 u16
    const size_t GCNT_N = (size_t)SUBB * 16;                // 50,000 int

    const size_t need = 3 * NQ * 2 + WFRAG_N * 2 + 384 * 4 + 64
                      + PACKED_N * 4 + OFFCNT_N * 4 + GS_N * 2 + GCNT_N * 4;

    if (ws_size < need) {
        sentinel_kernel<<<(out_size + 255) / 256, 256, 0, stream>>>((unsigned short*)d_out, out_size);
        return;
    }

    unsigned short* Qt  = (unsigned short*)d_ws;
    unsigned short* KVt = Qt + NQ;
    unsigned short* Wfrag = KVt + 2 * NQ;
    float* bias_f = (float*)(Wfrag + WFRAG_N);
    int* flag     = (int*)(bias_f + 384);
    unsigned int* packed = (unsigned int*)(flag + 16);
    unsigned int* offcnt = packed + PACKED_N;
    unsigned short* gsorted = (unsigned short*)(offcnt + OFFCNT_N);
    int* gcnt = (int*)(gsorted + GS_N);

    prep_kernel<<<24, 256, 0, stream>>>((const unsigned short*)h,
        Wq, bq, Wk, bk, Wv, bv, flag, Wfrag, bias_f);

    fused_gs_kernel<<<FUSED_BLOCKS, 256, 0, stream>>>(h, Wfrag, bias_f, flag,
        Qt, KVt, src, dst, packed, offcnt);

    sortbk_kernel<<<SUBB, 256, 0, stream>>>(packed, offcnt, gsorted, gcnt);

    bucket_agg_kernel<<<AGG_BLOCKS, 256, 0, stream>>>(Qt, KVt, gsorted, gcnt,
        flag, d_out);
}